// Round 1
// baseline (1216.771 us; speedup 1.0000x reference)
//
#include <hip/hip_runtime.h>
#include <math.h>

#define H 112
#define W 112
#define HW 12544
#define C 128
#define B 4
#define OCH 18
#define K2 9

// ---------------- weight transposes ----------------
// w_def [O=128, C=128, 9] -> wt [9][C][O]
__global__ void transpose_wdef(const float* __restrict__ w, float* __restrict__ wt) {
  int i = blockIdx.x * 256 + threadIdx.x;   // over 9*128*128
  if (i >= 9 * 128 * 128) return;
  int o = i & 127;
  int c = (i >> 7) & 127;
  int k = i >> 14;
  wt[i] = w[(o * 128 + c) * 9 + k];
}

// w_off [18, C, 9] -> wt [C][18][9]
__global__ void transpose_woff(const float* __restrict__ w, float* __restrict__ wt) {
  int i = blockIdx.x * 256 + threadIdx.x;   // over 128*18*9
  if (i >= 128 * 18 * 9) return;
  int k = i % 9;
  int oc = (i / 9) % 18;
  int c = i / (9 * 18);
  wt[i] = w[(oc * 128 + c) * 9 + k];
}

// ---------------- offset conv: [B,C,H,W] -> [B,18,H,W], 3x3 pad 1 ----------------
__global__ __launch_bounds__(256) void offset_conv(
    const float* __restrict__ x, const float* __restrict__ wt, // wt [C][18][9]
    const float* __restrict__ bias, float* __restrict__ out) {
  const int b = blockIdx.y;
  const int ho0 = blockIdx.x * 2;
  const int tid = threadIdx.x;
  const int r = tid >> 7;        // 0..1
  const int wo = tid & 127;      // active if < 112
  const int ho = ho0 + r;
  __shared__ float sx[4][114];
  __shared__ float sw[18 * 9];
  float acc[18];
#pragma unroll
  for (int i = 0; i < 18; i++) acc[i] = 0.f;
  const float* xb = x + (size_t)b * C * HW;
  for (int c = 0; c < C; c++) {
    for (int e = tid; e < 4 * 114; e += 256) {
      int j = e / 114, col = e % 114;
      int iy = ho0 - 1 + j, ix = col - 1;
      float v = 0.f;
      if (iy >= 0 && iy < H && ix >= 0 && ix < W) v = xb[c * HW + iy * W + ix];
      sx[j][col] = v;
    }
    for (int e = tid; e < 162; e += 256) sw[e] = wt[c * 162 + e];
    __syncthreads();
    if (wo < 112) {
      float xv[9];
#pragma unroll
      for (int ky = 0; ky < 3; ky++)
#pragma unroll
        for (int kx = 0; kx < 3; kx++)
          xv[ky * 3 + kx] = sx[r + ky][wo + kx];
#pragma unroll
      for (int oc = 0; oc < 18; oc++) {
        float a = acc[oc];
#pragma unroll
        for (int k = 0; k < 9; k++) a += sw[oc * 9 + k] * xv[k];
        acc[oc] = a;
      }
    }
    __syncthreads();
  }
  if (wo < 112) {
#pragma unroll
    for (int oc = 0; oc < 18; oc++)
      out[((size_t)(b * OCH + oc) * HW) + ho * W + wo] = acc[oc] + bias[oc];
  }
}

// ---------------- deformable conv: gather + GEMM ----------------
// out[b,o,p] = sum_{c,k2} w[o,c,k2] * bilinear(x[b,c], p, k2, offset)
__global__ __launch_bounds__(256) void deform_conv(
    const float* __restrict__ x,    // [B,C,H,W]
    const float* __restrict__ off,  // [B,18,H,W]
    const float* __restrict__ wt,   // [9][C][128]
    float* __restrict__ out) {      // [B,128,H,W]
  const int b = blockIdx.y;
  const int p0 = blockIdx.x * 64;
  const int tid = threadIdx.x;
  __shared__ int s_idx[K2][4][64];
  __shared__ float s_wgt[K2][4][64];
  __shared__ float s_smp[16][64];
  __shared__ float s_w[16][128];

  // precompute bilinear corners for the 64 pixels x 9 taps
  for (int e = tid; e < K2 * 64; e += 256) {
    int k2 = e / 64, pp = e % 64;
    int p = p0 + pp;
    int ho = p / W, wo = p % W;
    int ky = k2 / 3, kx = k2 % 3;
    float py = (float)(ky + ho - 1) + off[((size_t)(b * OCH + 2 * k2 + 0) * HW) + p];
    float px = (float)(kx + wo - 1) + off[((size_t)(b * OCH + 2 * k2 + 1) * HW) + p];
    float y0f = floorf(py), x0f = floorf(px);
    int y0 = (int)y0f, x0 = (int)x0f;
    float wy = py - y0f, wx = px - x0f;
#pragma unroll
    for (int j = 0; j < 4; j++) {
      int yi = y0 + (j >> 1), xi = x0 + (j & 1);
      bool vld = (yi >= 0 && yi < H && xi >= 0 && xi < W);
      float cw = ((j >> 1) ? wy : 1.f - wy) * ((j & 1) ? wx : 1.f - wx);
      int yc = min(max(yi, 0), H - 1), xc = min(max(xi, 0), W - 1);
      s_idx[k2][j][pp] = yc * W + xc;
      s_wgt[k2][j][pp] = vld ? cw : 0.f;
    }
  }

  float acc[4][8];
#pragma unroll
  for (int i = 0; i < 4; i++)
#pragma unroll
    for (int j = 0; j < 8; j++) acc[i][j] = 0.f;
  const int to = tid & 31;   // o block: to*4
  const int tp = tid >> 5;   // p block: tp*8
  __syncthreads();

  for (int k2 = 0; k2 < K2; k2++) {
    for (int c0 = 0; c0 < C; c0 += 16) {
      // stage weights [16][128]
#pragma unroll
      for (int i = 0; i < 8; i++) {
        int e = tid + i * 256;
        int ci = e >> 7, o = e & 127;
        s_w[ci][o] = wt[((size_t)(k2 * C) + (c0 + ci)) * 128 + o];
      }
      // stage samples [16][64]
#pragma unroll
      for (int i = 0; i < 4; i++) {
        int e = tid + i * 256;
        int ci = e >> 6, pp = e & 63;
        const float* xc = x + (size_t)(b * C + c0 + ci) * HW;
        float v = 0.f;
#pragma unroll
        for (int j = 0; j < 4; j++)
          v += s_wgt[k2][j][pp] * xc[s_idx[k2][j][pp]];
        s_smp[ci][pp] = v;
      }
      __syncthreads();
#pragma unroll
      for (int ci = 0; ci < 16; ci++) {
        float4 wv = *(const float4*)&s_w[ci][to * 4];
        float4 sv0 = *(const float4*)&s_smp[ci][tp * 8];
        float4 sv1 = *(const float4*)&s_smp[ci][tp * 8 + 4];
        float wv4[4] = {wv.x, wv.y, wv.z, wv.w};
        float sv[8] = {sv0.x, sv0.y, sv0.z, sv0.w, sv1.x, sv1.y, sv1.z, sv1.w};
#pragma unroll
        for (int i = 0; i < 4; i++)
#pragma unroll
          for (int j = 0; j < 8; j++) acc[i][j] += wv4[i] * sv[j];
      }
      __syncthreads();
    }
  }
#pragma unroll
  for (int i = 0; i < 4; i++) {
    int o = to * 4 + i;
    float* op = out + ((size_t)(b * C + o) * HW) + p0 + tp * 8;
    *(float4*)op = make_float4(acc[i][0], acc[i][1], acc[i][2], acc[i][3]);
    *(float4*)(op + 4) = make_float4(acc[i][4], acc[i][5], acc[i][6], acc[i][7]);
  }
}

// ---------------- BN stats: per-channel mean/var over (B,H,W) ----------------
__global__ __launch_bounds__(256) void bn_stats(const float* __restrict__ z, float* __restrict__ stats) {
  const int c = blockIdx.x;
  const int tid = threadIdx.x;
  float s = 0.f, sq = 0.f;
  for (int b = 0; b < B; b++) {
    const float* zp = z + (size_t)(b * C + c) * HW;
    for (int i = tid; i < HW; i += 256) {
      float v = zp[i];
      s += v;
      sq += v * v;
    }
  }
  __shared__ float ss[256], s2[256];
  ss[tid] = s;
  s2[tid] = sq;
  __syncthreads();
  for (int d = 128; d > 0; d >>= 1) {
    if (tid < d) {
      ss[tid] += ss[tid + d];
      s2[tid] += s2[tid + d];
    }
    __syncthreads();
  }
  if (tid == 0) {
    float N = (float)(B * HW);
    float m = ss[0] / N;
    float var = s2[0] / N - m * m;
    stats[c] = m;
    stats[C + c] = var;
  }
}

// ---------------- BN apply + exact GELU (+ optional residual) ----------------
template <bool RES>
__global__ __launch_bounds__(256) void bn_gelu_kernel(
    const float* __restrict__ z, const float* __restrict__ stats,
    const float* __restrict__ gamma, const float* __restrict__ beta,
    const float* __restrict__ resid, float* __restrict__ out) {
  int i4 = blockIdx.x * 256 + threadIdx.x;
  const int total = B * C * HW / 4;
  if (i4 >= total) return;
  int c = ((i4 * 4) / HW) % C;
  float m = stats[c];
  float v = stats[C + c];
  float rs = rsqrtf(v + 1e-5f) * gamma[c];
  float bb = beta[c];
  float4 zv = ((const float4*)z)[i4];
  float r[4] = {zv.x, zv.y, zv.z, zv.w};
#pragma unroll
  for (int j = 0; j < 4; j++) {
    float xn = (r[j] - m) * rs + bb;
    r[j] = 0.5f * xn * (1.f + erff(xn * 0.70710678118654752f));
  }
  if (RES) {
    float4 rv = ((const float4*)resid)[i4];
    r[0] += rv.x;
    r[1] += rv.y;
    r[2] += rv.z;
    r[3] += rv.w;
  }
  ((float4*)out)[i4] = make_float4(r[0], r[1], r[2], r[3]);
}

extern "C" void kernel_launch(void* const* d_in, const int* in_sizes, int n_in,
                              void* d_out, int out_size, void* d_ws, size_t ws_size,
                              hipStream_t stream) {
  const float* x = (const float*)d_in[0];
  const float* w_off1 = (const float*)d_in[1];
  const float* b_off1 = (const float*)d_in[2];
  const float* w_def1 = (const float*)d_in[3];
  const float* gamma1 = (const float*)d_in[4];
  const float* beta1 = (const float*)d_in[5];
  const float* w_off2 = (const float*)d_in[6];
  const float* b_off2 = (const float*)d_in[7];
  const float* w_def2 = (const float*)d_in[8];
  const float* gamma2 = (const float*)d_in[9];
  const float* beta2 = (const float*)d_in[10];
  float* out = (float*)d_out;

  char* ws = (char*)d_ws;
  float* ws_z = (float*)ws;                                   // 25,690,112 B
  float* ws_off = (float*)(ws + 25690112);                    //  3,612,672 B
  float* ws_wdt = (float*)(ws + 25690112 + 3612672);          //    589,824 B
  float* ws_wot = (float*)(ws + 25690112 + 3612672 + 589824); //     82,944 B
  float* ws_st = (float*)(ws + 25690112 + 3612672 + 589824 + 82944); // 1 KB

  const int elem4 = B * C * HW / 4;           // 1,605,632
  const int eg = (elem4 + 255) / 256;         // 6272

  // ---- block 1 ----
  transpose_woff<<<(128 * 18 * 9 + 255) / 256, 256, 0, stream>>>(w_off1, ws_wot);
  transpose_wdef<<<(9 * 128 * 128 + 255) / 256, 256, 0, stream>>>(w_def1, ws_wdt);
  offset_conv<<<dim3(56, 4), 256, 0, stream>>>(x, ws_wot, b_off1, ws_off);
  deform_conv<<<dim3(196, 4), 256, 0, stream>>>(x, ws_off, ws_wdt, ws_z);
  bn_stats<<<128, 256, 0, stream>>>(ws_z, ws_st);
  bn_gelu_kernel<false><<<eg, 256, 0, stream>>>(ws_z, ws_st, gamma1, beta1, nullptr, out);

  // ---- block 2 (y1 lives in d_out) ----
  transpose_woff<<<(128 * 18 * 9 + 255) / 256, 256, 0, stream>>>(w_off2, ws_wot);
  transpose_wdef<<<(9 * 128 * 128 + 255) / 256, 256, 0, stream>>>(w_def2, ws_wdt);
  offset_conv<<<dim3(56, 4), 256, 0, stream>>>(out, ws_wot, b_off2, ws_off);
  deform_conv<<<dim3(196, 4), 256, 0, stream>>>(out, ws_off, ws_wdt, ws_z);
  bn_stats<<<128, 256, 0, stream>>>(ws_z, ws_st);
  bn_gelu_kernel<true><<<eg, 256, 0, stream>>>(ws_z, ws_st, gamma2, beta2, x, out);
}

// Round 2
// 418.049 us; speedup vs baseline: 2.9106x; 2.9106x over previous
//
#include <hip/hip_runtime.h>
#include <hip/hip_bf16.h>
#include <math.h>

#define HW 12544
#define NPX 50176   // B*HW
#define CC 128
#define BB 4

typedef short bf16x8 __attribute__((ext_vector_type(8)));
typedef float f32x4 __attribute__((ext_vector_type(4)));

__device__ __forceinline__ float bf2f(unsigned int u16) {
  union { unsigned int i; float f; } v; v.i = u16 << 16; return v.f;
}
__device__ __forceinline__ unsigned short f2bf(float f) {
  __hip_bfloat16 h = __float2bfloat16(f);
  return *reinterpret_cast<unsigned short*>(&h);
}
__device__ __forceinline__ float gelu(float v) {
  return 0.5f * v * (1.f + erff(v * 0.70710678118654752f));
}

// ---- x NCHW fp32 -> xh NHWC bf16 ----
__global__ __launch_bounds__(256) void to_nhwc(const float* __restrict__ x,
                                               unsigned short* __restrict__ xh) {
  const int pt = blockIdx.x, ct = blockIdx.y, b = blockIdx.z;
  const int p0 = pt * 32, c0 = ct * 32;
  const int tid = threadIdx.x;
  __shared__ float ls[32][33];
  int col = tid & 31, r = tid >> 5;
#pragma unroll
  for (int i = 0; i < 4; i++) {
    int c = c0 + r + i * 8;
    ls[r + i * 8][col] = x[((size_t)(b * CC) + c) * HW + p0 + col];
  }
  __syncthreads();
  int px = tid >> 3, cq = (tid & 7) * 4;
  ushort4 v;
  v.x = f2bf(ls[cq + 0][px]);
  v.y = f2bf(ls[cq + 1][px]);
  v.z = f2bf(ls[cq + 2][px]);
  v.w = f2bf(ls[cq + 3][px]);
  *(ushort4*)&xh[((size_t)(b * HW) + p0 + px) * CC + c0 + cq] = v;
}

// ---- pack w_def [O=128][C=128][9] -> [9][128 o][128 c] bf16, pre-swizzled ----
__global__ void pack_wdef(const float* __restrict__ w, unsigned short* __restrict__ wpk) {
  int i = blockIdx.x * 256 + threadIdx.x;      // 9*16384
  int k2 = i >> 14;
  int r = i & 16383;
  int o = r >> 7;
  int c = (r & 127) ^ ((o & 7) << 3);
  wpk[i] = f2bf(w[(o * CC + c) * 9 + k2]);
}

// ---- pack w_off [18][128][9] -> [9][32 o][128 c] bf16 (o>=18 zero), pre-swizzled ----
__global__ void pack_woff(const float* __restrict__ w, unsigned short* __restrict__ wpk) {
  int i = blockIdx.x * 256 + threadIdx.x;      // 9*4096
  int k2 = i >> 12;
  int r = i & 4095;
  int o = r >> 7;
  int c = (r & 127) ^ ((o & 7) << 3);
  wpk[i] = (o < 18) ? f2bf(w[(o * CC + c) * 9 + k2]) : (unsigned short)0;
}

// ---- offset conv via MFMA: xh -> offs [B*HW][18] fp32 ----
__global__ __launch_bounds__(256) void offset_mfma(
    const unsigned short* __restrict__ xh, const unsigned short* __restrict__ wopk,
    const float* __restrict__ boff, float* __restrict__ offs) {
  const int b = blockIdx.y;
  const int p0 = blockIdx.x * 64;
  const int tid = threadIdx.x;
  const int l = tid & 63, w = tid >> 6;
  __shared__ unsigned short s_w[32 * 128];
  __shared__ unsigned short s_smp[64 * 128];
  f32x4 acc[2];
  acc[0] = (f32x4){0.f, 0.f, 0.f, 0.f};
  acc[1] = (f32x4){0.f, 0.f, 0.f, 0.f};
  const unsigned short* xb = xh + (size_t)b * HW * CC;
  const int hl = l & 31, ph = l >> 5;
  for (int k2 = 0; k2 < 9; k2++) {
    const int ky = k2 / 3, kx = k2 - 3 * ky;
    {
      const unsigned short* src = wopk + k2 * 4096;
#pragma unroll
      for (int i = 0; i < 2; i++) {
        int e = tid * 8 + i * 2048;
        *(bf16x8*)&s_w[e] = *(const bf16x8*)&src[e];
      }
    }
#pragma unroll
    for (int s = 0; s < 8; s++) {
      int pxl = w * 16 + s * 2 + ph;
      int p = p0 + pxl;
      int ho = p / 112, wo = p - ho * 112;
      int y = ho + ky - 1, x = wo + kx - 1;
      uint2 v = make_uint2(0u, 0u);
      if (y >= 0 && y < 112 && x >= 0 && x < 112)
        v = *(const uint2*)&xb[(size_t)(y * 112 + x) * CC + hl * 4];
      int ba = (pxl * 256 + hl * 8) ^ ((pxl & 7) << 4);
      *(uint2*)((char*)s_smp + ba) = v;
    }
    __syncthreads();
    const int row = l & 15, grp = l >> 4;
#pragma unroll
    for (int ks = 0; ks < 4; ks++) {
      int pxr = w * 16 + row;
      bf16x8 bf = *(const bf16x8*)((const char*)s_smp +
                   ((pxr * 256 + ks * 64 + grp * 16) ^ ((pxr & 7) << 4)));
#pragma unroll
      for (int m = 0; m < 2; m++) {
        int o = m * 16 + row;
        bf16x8 af = *(const bf16x8*)((const char*)s_w +
                     ((o * 256 + ks * 64 + grp * 16) ^ ((o & 7) << 4)));
        acc[m] = __builtin_amdgcn_mfma_f32_16x16x32_bf16(af, bf, acc[m], 0, 0, 0);
      }
    }
    __syncthreads();
  }
  const int row = l & 15, grp = l >> 4;
  int p = p0 + w * 16 + row;
  float* op = offs + (size_t)(b * HW + p) * 18;
#pragma unroll
  for (int m = 0; m < 2; m++)
#pragma unroll
    for (int r = 0; r < 4; r++) {
      int o = m * 16 + grp * 4 + r;
      if (o < 18) op[o] = acc[m][r] + boff[o];
    }
}

// ---- deformable conv via MFMA: xh, offs -> z NHWC fp32 ----
__global__ __launch_bounds__(256) void deform_mfma(
    const unsigned short* __restrict__ xh, const float* __restrict__ offs,
    const unsigned short* __restrict__ wpk, float* __restrict__ z) {
  const int b = blockIdx.y;
  const int p0 = blockIdx.x * 64;
  const int tid = threadIdx.x;
  const int l = tid & 63, w = tid >> 6;
  __shared__ unsigned short s_w[128 * 128];
  __shared__ unsigned short s_smp[64 * 128];
  f32x4 acc[2][4];
#pragma unroll
  for (int m = 0; m < 2; m++)
#pragma unroll
    for (int n = 0; n < 4; n++) acc[m][n] = (f32x4){0.f, 0.f, 0.f, 0.f};
  const unsigned short* xb = xh + (size_t)b * HW * CC;
  const int hl = l & 31, ph = l >> 5;
  for (int k2 = 0; k2 < 9; k2++) {
    const int ky = k2 / 3, kx = k2 - 3 * ky;
    {
      const unsigned short* src = wpk + k2 * 16384;
#pragma unroll
      for (int i = 0; i < 8; i++) {
        int e = tid * 8 + i * 2048;
        *(bf16x8*)&s_w[e] = *(const bf16x8*)&src[e];
      }
    }
#pragma unroll
    for (int s = 0; s < 8; s++) {
      int pxl = w * 16 + s * 2 + ph;
      int p = p0 + pxl;
      int ho = p / 112, wo = p - ho * 112;
      const float2 dv = *(const float2*)&offs[(size_t)(b * HW + p) * 18 + k2 * 2];
      float py = (float)(ho + ky - 1) + dv.x;
      float pxf = (float)(wo + kx - 1) + dv.y;
      float y0f = floorf(py), x0f = floorf(pxf);
      float wy = py - y0f, wx = pxf - x0f;
      int y0 = (int)y0f, x0 = (int)x0f;
      int y1 = y0 + 1, x1 = x0 + 1;
      bool iy0 = (y0 >= 0) & (y0 < 112), iy1 = (y1 >= 0) & (y1 < 112);
      bool ix0 = (x0 >= 0) & (x0 < 112), ix1 = (x1 >= 0) & (x1 < 112);
      float v00 = (iy0 & ix0) ? (1.f - wy) * (1.f - wx) : 0.f;
      float v01 = (iy0 & ix1) ? (1.f - wy) * wx : 0.f;
      float v10 = (iy1 & ix0) ? wy * (1.f - wx) : 0.f;
      float v11 = (iy1 & ix1) ? wy * wx : 0.f;
      int y0c = min(max(y0, 0), 111), y1c = min(max(y1, 0), 111);
      int x0c = min(max(x0, 0), 111), x1c = min(max(x1, 0), 111);
      const unsigned short* r0 = xb + (size_t)(y0c * 112) * CC;
      const unsigned short* r1 = xb + (size_t)(y1c * 112) * CC;
      int c0 = hl * 4;
      uint2 a00 = *(const uint2*)&r0[x0c * CC + c0];
      uint2 a01 = *(const uint2*)&r0[x1c * CC + c0];
      uint2 a10 = *(const uint2*)&r1[x0c * CC + c0];
      uint2 a11 = *(const uint2*)&r1[x1c * CC + c0];
      float e0 = v00 * bf2f(a00.x & 0xffff) + v01 * bf2f(a01.x & 0xffff)
               + v10 * bf2f(a10.x & 0xffff) + v11 * bf2f(a11.x & 0xffff);
      float e1 = v00 * bf2f(a00.x >> 16) + v01 * bf2f(a01.x >> 16)
               + v10 * bf2f(a10.x >> 16) + v11 * bf2f(a11.x >> 16);
      float e2 = v00 * bf2f(a00.y & 0xffff) + v01 * bf2f(a01.y & 0xffff)
               + v10 * bf2f(a10.y & 0xffff) + v11 * bf2f(a11.y & 0xffff);
      float e3 = v00 * bf2f(a00.y >> 16) + v01 * bf2f(a01.y >> 16)
               + v10 * bf2f(a10.y >> 16) + v11 * bf2f(a11.y >> 16);
      unsigned int w0 = ((unsigned int)f2bf(e1) << 16) | f2bf(e0);
      unsigned int w1 = ((unsigned int)f2bf(e3) << 16) | f2bf(e2);
      int ba = (pxl * 256 + c0 * 2) ^ ((pxl & 7) << 4);
      *(uint2*)((char*)s_smp + ba) = make_uint2(w0, w1);
    }
    __syncthreads();
    const int row = l & 15, grp = l >> 4;
#pragma unroll
    for (int ks = 0; ks < 4; ks++) {
      bf16x8 bfr[4];
#pragma unroll
      for (int n = 0; n < 4; n++) {
        int px = n * 16 + row;
        bfr[n] = *(const bf16x8*)((const char*)s_smp +
                  ((px * 256 + ks * 64 + grp * 16) ^ ((px & 7) << 4)));
      }
#pragma unroll
      for (int m = 0; m < 2; m++) {
        int o = (w * 2 + m) * 16 + row;
        bf16x8 af = *(const bf16x8*)((const char*)s_w +
                     ((o * 256 + ks * 64 + grp * 16) ^ ((o & 7) << 4)));
#pragma unroll
        for (int n = 0; n < 4; n++)
          acc[m][n] = __builtin_amdgcn_mfma_f32_16x16x32_bf16(af, bfr[n], acc[m][n], 0, 0, 0);
      }
    }
    __syncthreads();
  }
  const int row = l & 15, grp = l >> 4;
#pragma unroll
  for (int m = 0; m < 2; m++)
#pragma unroll
    for (int n = 0; n < 4; n++) {
      int o = (w * 2 + m) * 16 + grp * 4;
      size_t px = (size_t)(b * HW) + p0 + n * 16 + row;
      float4 v = make_float4(acc[m][n][0], acc[m][n][1], acc[m][n][2], acc[m][n][3]);
      *(float4*)&z[px * CC + o] = v;
    }
}

// ---- BN stats stage 1: partial sums over 128-row chunks ----
__global__ __launch_bounds__(256) void bn_part(const float* __restrict__ z,
                                               float* __restrict__ part) {
  const int blk = blockIdx.x;   // 392
  const int tid = threadIdx.x;
  const int c4 = tid & 31, rg = tid >> 5;
  const float* base = z + (size_t)blk * 128 * CC;
  f32x4 s = (f32x4){0.f, 0.f, 0.f, 0.f};
  f32x4 q = (f32x4){0.f, 0.f, 0.f, 0.f};
#pragma unroll 4
  for (int i = 0; i < 16; i++) {
    f32x4 v = *(const f32x4*)&base[(size_t)(rg + i * 8) * CC + c4 * 4];
    s += v;
    q += v * v;
  }
  __shared__ float sm[8][128], sq[8][128];
  *(f32x4*)&sm[rg][c4 * 4] = s;
  *(f32x4*)&sq[rg][c4 * 4] = q;
  __syncthreads();
  if (tid < 128) {
    float a = 0.f, bsum = 0.f;
#pragma unroll
    for (int j = 0; j < 8; j++) { a += sm[j][tid]; bsum += sq[j][tid]; }
    part[blk * 256 + tid] = a;
    part[blk * 256 + 128 + tid] = bsum;
  }
}

// ---- BN stats stage 2 ----
__global__ void bn_fin(const float* __restrict__ part, const float* __restrict__ gamma,
                       const float* __restrict__ beta, float* __restrict__ stats) {
  int t = threadIdx.x;   // 128
  float s = 0.f, q = 0.f;
  for (int j = 0; j < 392; j++) { s += part[j * 256 + t]; q += part[j * 256 + 128 + t]; }
  float N = 50176.f;
  float m = s / N;
  float var = q / N - m * m;
  stats[t] = m;
  stats[128 + t] = rsqrtf(var + 1e-5f) * gamma[t];
  stats[256 + t] = beta[t];
}

// ---- BN+GELU, NHWC fp32 -> NHWC bf16 (feeds block 2) ----
__global__ __launch_bounds__(256) void bn_gelu_to_bf16(
    const float* __restrict__ z, const float* __restrict__ stats,
    unsigned short* __restrict__ yh) {
  int i4 = blockIdx.x * 256 + threadIdx.x;   // 1,605,632 total (exact grid)
  int c0 = (i4 & 31) * 4;
  f32x4 m = *(const f32x4*)&stats[c0];
  f32x4 rg = *(const f32x4*)&stats[128 + c0];
  f32x4 bt = *(const f32x4*)&stats[256 + c0];
  f32x4 v = ((const f32x4*)z)[i4];
  ushort4 o;
  o.x = f2bf(gelu((v[0] - m[0]) * rg[0] + bt[0]));
  o.y = f2bf(gelu((v[1] - m[1]) * rg[1] + bt[1]));
  o.z = f2bf(gelu((v[2] - m[2]) * rg[2] + bt[2]));
  o.w = f2bf(gelu((v[3] - m[3]) * rg[3] + bt[3]));
  *(ushort4*)&yh[(size_t)i4 * 4] = o;
}

// ---- final: BN+GELU on z2 NHWC, transpose to NCHW, +residual x ----
__global__ __launch_bounds__(256) void bn_gelu_final(
    const float* __restrict__ z, const float* __restrict__ stats,
    const float* __restrict__ x, float* __restrict__ out) {
  const int pt = blockIdx.x, b = blockIdx.y;
  const int p0 = pt * 16;
  const int tid = threadIdx.x;
  __shared__ float ls[16][129];
  {
    int cq = tid & 15, r = tid >> 4;
    const float* zr = z + ((size_t)(b * HW) + p0 + r) * CC + cq * 8;
    f32x4 v0 = *(const f32x4*)&zr[0];
    f32x4 v1 = *(const f32x4*)&zr[4];
    f32x4 m0 = *(const f32x4*)&stats[cq * 8];
    f32x4 m1 = *(const f32x4*)&stats[cq * 8 + 4];
    f32x4 r0 = *(const f32x4*)&stats[128 + cq * 8];
    f32x4 r1 = *(const f32x4*)&stats[128 + cq * 8 + 4];
    f32x4 b0 = *(const f32x4*)&stats[256 + cq * 8];
    f32x4 b1 = *(const f32x4*)&stats[256 + cq * 8 + 4];
#pragma unroll
    for (int j = 0; j < 4; j++) {
      ls[r][cq * 8 + j] = gelu((v0[j] - m0[j]) * r0[j] + b0[j]);
      ls[r][cq * 8 + 4 + j] = gelu((v1[j] - m1[j]) * r1[j] + b1[j]);
    }
  }
  __syncthreads();
  int c = tid & 127, half = tid >> 7;
  const float* xr = x + ((size_t)(b * CC) + c) * HW + p0 + half * 8;
  float* orow = out + ((size_t)(b * CC) + c) * HW + p0 + half * 8;
  float4 o1 = make_float4(ls[half * 8 + 0][c], ls[half * 8 + 1][c],
                          ls[half * 8 + 2][c], ls[half * 8 + 3][c]);
  float4 o2 = make_float4(ls[half * 8 + 4][c], ls[half * 8 + 5][c],
                          ls[half * 8 + 6][c], ls[half * 8 + 7][c]);
  float4 x1 = *(const float4*)&xr[0];
  float4 x2 = *(const float4*)&xr[4];
  o1.x += x1.x; o1.y += x1.y; o1.z += x1.z; o1.w += x1.w;
  o2.x += x2.x; o2.y += x2.y; o2.z += x2.z; o2.w += x2.w;
  *(float4*)&orow[0] = o1;
  *(float4*)&orow[4] = o2;
}

extern "C" void kernel_launch(void* const* d_in, const int* in_sizes, int n_in,
                              void* d_out, int out_size, void* d_ws, size_t ws_size,
                              hipStream_t stream) {
  const float* x = (const float*)d_in[0];
  const float* w_off1 = (const float*)d_in[1];
  const float* b_off1 = (const float*)d_in[2];
  const float* w_def1 = (const float*)d_in[3];
  const float* gamma1 = (const float*)d_in[4];
  const float* beta1 = (const float*)d_in[5];
  const float* w_off2 = (const float*)d_in[6];
  const float* b_off2 = (const float*)d_in[7];
  const float* w_def2 = (const float*)d_in[8];
  const float* gamma2 = (const float*)d_in[9];
  const float* beta2 = (const float*)d_in[10];
  float* out = (float*)d_out;

  char* ws = (char*)d_ws;
  unsigned short* xhb = (unsigned short*)ws;          // 12,845,056 B (x-nhwc, later y1h)
  float* zb = (float*)(ws + 12845056);                // 25,690,112 B
  float* offb = (float*)(ws + 38535168);              //  3,612,672 B
  unsigned short* wpkb = (unsigned short*)(ws + 42147840);   // 294,912 B
  unsigned short* wopkb = (unsigned short*)(ws + 42442752);  //  73,728 B
  float* partb = (float*)(ws + 42516480);             //    401,408 B
  float* statsb = (float*)(ws + 42917888);            //      1,536 B

  to_nhwc<<<dim3(392, 4, 4), 256, 0, stream>>>(x, xhb);

  // ---- block 1 ----
  pack_woff<<<144, 256, 0, stream>>>(w_off1, wopkb);
  pack_wdef<<<576, 256, 0, stream>>>(w_def1, wpkb);
  offset_mfma<<<dim3(196, 4), 256, 0, stream>>>(xhb, wopkb, b_off1, offb);
  deform_mfma<<<dim3(196, 4), 256, 0, stream>>>(xhb, offb, wpkb, zb);
  bn_part<<<392, 256, 0, stream>>>(zb, partb);
  bn_fin<<<1, 128, 0, stream>>>(partb, gamma1, beta1, statsb);
  bn_gelu_to_bf16<<<6272, 256, 0, stream>>>(zb, statsb, xhb);

  // ---- block 2 ----
  pack_woff<<<144, 256, 0, stream>>>(w_off2, wopkb);
  pack_wdef<<<576, 256, 0, stream>>>(w_def2, wpkb);
  offset_mfma<<<dim3(196, 4), 256, 0, stream>>>(xhb, wopkb, b_off2, offb);
  deform_mfma<<<dim3(196, 4), 256, 0, stream>>>(xhb, offb, wpkb, zb);
  bn_part<<<392, 256, 0, stream>>>(zb, partb);
  bn_fin<<<1, 128, 0, stream>>>(partb, gamma2, beta2, statsb);
  bn_gelu_final<<<dim3(784, 4), 256, 0, stream>>>(zb, statsb, x, out);
}

// Round 3
// 250.144 us; speedup vs baseline: 4.8643x; 1.6712x over previous
//
#include <hip/hip_runtime.h>
#include <hip/hip_bf16.h>
#include <math.h>

#define HW 12544
#define CC 128
#define BB 4

typedef short bf16x8 __attribute__((ext_vector_type(8)));
typedef float f32x4 __attribute__((ext_vector_type(4)));

__device__ __forceinline__ float bf2f(unsigned int u) {
  union { unsigned int i; float f; } v; v.i = u << 16; return v.f;
}
__device__ __forceinline__ unsigned short f2bf(float f) {
  __hip_bfloat16 h = __float2bfloat16(f);
  return *reinterpret_cast<unsigned short*>(&h);
}
__device__ __forceinline__ float gelu(float v) {
  return 0.5f * v * (1.f + erff(v * 0.70710678118654752f));
}

// ---- x NCHW fp32 -> xh NHWC bf16 ----
__global__ __launch_bounds__(256) void to_nhwc(const float* __restrict__ x,
                                               unsigned short* __restrict__ xh) {
  const int pt = blockIdx.x, ct = blockIdx.y, b = blockIdx.z;
  const int p0 = pt * 32, c0 = ct * 32;
  const int tid = threadIdx.x;
  __shared__ float ls[32][33];
  int col = tid & 31, r = tid >> 5;
#pragma unroll
  for (int i = 0; i < 4; i++) {
    int c = c0 + r + i * 8;
    ls[r + i * 8][col] = x[((size_t)(b * CC) + c) * HW + p0 + col];
  }
  __syncthreads();
  int px = tid >> 3, cq = (tid & 7) * 4;
  ushort4 v;
  v.x = f2bf(ls[cq + 0][px]);
  v.y = f2bf(ls[cq + 1][px]);
  v.z = f2bf(ls[cq + 2][px]);
  v.w = f2bf(ls[cq + 3][px]);
  *(ushort4*)&xh[((size_t)(b * HW) + p0 + px) * CC + c0 + cq] = v;
}

// ---- pack w_def [O=128][C=128][9] -> fragment-line layout ----
// elem i = (((k2*8+mo)*4+ks)*64+lane)*8+j  ->  w[o=mo*16+(lane&15)][c=ks*32+(lane>>4)*8+j][k2]
__global__ void pack_wdef(const float* __restrict__ w, unsigned short* __restrict__ wpk) {
  int i = blockIdx.x * 256 + threadIdx.x;   // 147456
  int j = i & 7;
  int lane = (i >> 3) & 63;
  int ks = (i >> 9) & 3;
  int mo = (i >> 11) & 7;
  int k2 = i >> 14;
  int o = mo * 16 + (lane & 15);
  int c = ks * 32 + ((lane >> 4) << 3) + j;
  wpk[i] = f2bf(w[(o * CC + c) * 9 + k2]);
}

// ---- pack w_off [18][C][9] -> fragment-line layout, M padded to 32 ----
__global__ void pack_woff(const float* __restrict__ w, unsigned short* __restrict__ wpk) {
  int i = blockIdx.x * 256 + threadIdx.x;   // 36864
  int j = i & 7;
  int lane = (i >> 3) & 63;
  int ks = (i >> 9) & 3;
  int mo = (i >> 11) & 1;
  int k2 = i >> 12;
  int o = mo * 16 + (lane & 15);
  int c = ks * 32 + ((lane >> 4) << 3) + j;
  wpk[i] = (o < 18) ? f2bf(w[(o * CC + c) * 9 + k2]) : (unsigned short)0;
}

// ---- offset conv via MFMA (barrier-free, dbuf, weights in regs) ----
// writes offs2 layout: float2 at [(b*9 + k2)*HW + p]
__global__ __launch_bounds__(256) void offset_mfma(
    const unsigned short* __restrict__ xh, const unsigned short* __restrict__ wopk,
    const float* __restrict__ boff, float* __restrict__ offs2) {
  const int b = blockIdx.y;
  const int p0 = blockIdx.x * 64;
  const int tid = threadIdx.x;
  const int l = tid & 63, w = tid >> 6;
  const int hl = l & 31, ph = l >> 5;
  const int row = l & 15, grp = l >> 4;
  __shared__ unsigned short s_smp[2][8192];
  const unsigned short* xb = xh + (size_t)b * HW * CC + hl * 4;
  f32x4 acc[2];
  acc[0] = (f32x4){0.f, 0.f, 0.f, 0.f};
  acc[1] = (f32x4){0.f, 0.f, 0.f, 0.f};
  uint2 g[4];
  bf16x8 af[2][4];

#define OISSUE(k2t, sB)                                                        \
  {                                                                            \
    int ky = (k2t) / 3, kx = (k2t) - 3 * ((k2t) / 3);                          \
    _Pragma("unroll") for (int s = 0; s < 4; s++) {                            \
      int pxl = w * 16 + (sB + s) * 2 + ph;                                    \
      int p = p0 + pxl;                                                        \
      int ho = p / 112, wo = p - ho * 112;                                     \
      int y = ho + ky - 1, x = wo + kx - 1;                                    \
      bool vld = ((unsigned)y < 112u) & ((unsigned)x < 112u);                  \
      uint2 t = make_uint2(0u, 0u);                                            \
      if (vld) t = *(const uint2*)&xb[(size_t)(y * 112 + x) * CC];             \
      g[s] = t;                                                                \
    }                                                                          \
  }

#define OCOMMIT(sB, buf)                                                       \
  _Pragma("unroll") for (int s = 0; s < 4; s++) {                              \
    int pxl = w * 16 + (sB + s) * 2 + ph;                                      \
    *(uint2*)((char*)&s_smp[buf][0] +                                          \
              ((pxl * 256 + hl * 8) ^ ((pxl & 7) << 4))) = g[s];               \
  }

#define OMFMA(ksB)                                                             \
  __builtin_amdgcn_s_setprio(1);                                               \
  _Pragma("unroll") for (int ks = ksB; ks < ksB + 2; ks++) {                   \
    int pxr = w * 16 + row;                                                    \
    bf16x8 bfr = *(const bf16x8*)((const char*)&s_smp[cur][0] +                \
                 ((pxr * 256 + ks * 64 + grp * 16) ^ ((pxr & 7) << 4)));       \
    _Pragma("unroll") for (int m = 0; m < 2; m++)                              \
      acc[m] = __builtin_amdgcn_mfma_f32_16x16x32_bf16(af[m][ks], bfr, acc[m], 0, 0, 0); \
  }                                                                            \
  __builtin_amdgcn_s_setprio(0);

  // prologue: gather k2=0 into buf0
  OISSUE(0, 0); OCOMMIT(0, 0);
  OISSUE(0, 4); OCOMMIT(4, 0);
  int cur = 0;
  for (int k2 = 0; k2 < 9; k2++) {
    const unsigned short* wb = wopk + (size_t)(k2 * 2) * 2048;
#pragma unroll
    for (int m = 0; m < 2; m++)
#pragma unroll
      for (int ks = 0; ks < 4; ks++)
        af[m][ks] = *(const bf16x8*)&wb[(m * 4 + ks) * 512 + l * 8];
    if (k2 < 8) { OISSUE(k2 + 1, 0); }
    OMFMA(0);
    if (k2 < 8) { OCOMMIT(0, cur ^ 1); OISSUE(k2 + 1, 4); }
    OMFMA(2);
    if (k2 < 8) { OCOMMIT(4, cur ^ 1); }
    cur ^= 1;
  }
  // epilogue: acc[m][r] -> o = m*16 + grp*4 + r, pixel p = p0 + w*16 + row
  int p = p0 + w * 16 + row;
  {
    float2 w0 = make_float2(acc[0][0] + boff[grp * 4 + 0], acc[0][1] + boff[grp * 4 + 1]);
    float2 w1 = make_float2(acc[0][2] + boff[grp * 4 + 2], acc[0][3] + boff[grp * 4 + 3]);
    *(float2*)&offs2[((size_t)(b * 9 + grp * 2) * HW + p) * 2] = w0;
    *(float2*)&offs2[((size_t)(b * 9 + grp * 2 + 1) * HW + p) * 2] = w1;
    if (grp == 0) {
      float2 w2 = make_float2(acc[1][0] + boff[16], acc[1][1] + boff[17]);
      *(float2*)&offs2[((size_t)(b * 9 + 8) * HW + p) * 2] = w2;
    }
  }
#undef OISSUE
#undef OCOMMIT
#undef OMFMA
}

// ---- deformable conv via MFMA (dbuf, coord table, weights in regs) ----
__global__ __launch_bounds__(256) void deform_mfma(
    const unsigned short* __restrict__ xh, const float* __restrict__ offs2,
    const unsigned short* __restrict__ wpk, float* __restrict__ z) {
  const int b = blockIdx.y;
  const int p0 = blockIdx.x * 64;
  const int tid = threadIdx.x;
  const int l = tid & 63, w = tid >> 6;
  const int hl = l & 31, ph = l >> 5;
  const int row = l & 15, grp = l >> 4;
  __shared__ unsigned short s_smp[2][8192];
  __shared__ uint4 s_coord[9][64];

  // ---- coord precompute: clamped u16 corner indices + bf16 corner weights ----
  for (int e = tid; e < 576; e += 256) {
    int k2 = e >> 6, px = e & 63;
    int p = p0 + px;
    int ho = p / 112, wo = p - ho * 112;
    int ky = k2 / 3, kx = k2 - 3 * ky;
    float2 dv = *(const float2*)&offs2[((size_t)(b * 9 + k2) * HW + p) * 2];
    float py = (float)(ho + ky - 1) + dv.x;
    float pxf = (float)(wo + kx - 1) + dv.y;
    float y0f = floorf(py), x0f = floorf(pxf);
    float wy = py - y0f, wx = pxf - x0f;
    int y0 = (int)y0f, x0 = (int)x0f;
    int y1 = y0 + 1, x1 = x0 + 1;
    bool iy0 = ((unsigned)y0 < 112u), iy1 = ((unsigned)y1 < 112u);
    bool ix0 = ((unsigned)x0 < 112u), ix1 = ((unsigned)x1 < 112u);
    float v00 = (iy0 & ix0) ? (1.f - wy) * (1.f - wx) : 0.f;
    float v01 = (iy0 & ix1) ? (1.f - wy) * wx : 0.f;
    float v10 = (iy1 & ix0) ? wy * (1.f - wx) : 0.f;
    float v11 = (iy1 & ix1) ? wy * wx : 0.f;
    int y0c = min(max(y0, 0), 111), y1c = min(max(y1, 0), 111);
    int x0c = min(max(x0, 0), 111), x1c = min(max(x1, 0), 111);
    uint4 ce;
    ce.x = (unsigned)(y0c * 112 + x0c) | ((unsigned)(y0c * 112 + x1c) << 16);
    ce.y = (unsigned)(y1c * 112 + x0c) | ((unsigned)(y1c * 112 + x1c) << 16);
    ce.z = (unsigned)f2bf(v00) | ((unsigned)f2bf(v01) << 16);
    ce.w = (unsigned)f2bf(v10) | ((unsigned)f2bf(v11) << 16);
    s_coord[k2][px] = ce;
  }

  const unsigned short* xb = xh + (size_t)b * HW * CC + hl * 4;
  f32x4 acc[2][4];
#pragma unroll
  for (int m = 0; m < 2; m++)
#pragma unroll
    for (int n = 0; n < 4; n++) acc[m][n] = (f32x4){0.f, 0.f, 0.f, 0.f};
  uint2 g[4][4];
  uint4 ce[4];
  bf16x8 af[2][4];
  __syncthreads();

#define DISSUE(k2t, sB)                                                        \
  _Pragma("unroll") for (int s = 0; s < 4; s++) {                              \
    int pxl = w * 16 + (sB + s) * 2 + ph;                                      \
    ce[s] = s_coord[k2t][pxl];                                                 \
    g[s][0] = *(const uint2*)&xb[(size_t)(ce[s].x & 0xffffu) * CC];            \
    g[s][1] = *(const uint2*)&xb[(size_t)(ce[s].x >> 16) * CC];                \
    g[s][2] = *(const uint2*)&xb[(size_t)(ce[s].y & 0xffffu) * CC];            \
    g[s][3] = *(const uint2*)&xb[(size_t)(ce[s].y >> 16) * CC];                \
  }

#define DCOMMIT(sB, buf)                                                       \
  _Pragma("unroll") for (int s = 0; s < 4; s++) {                              \
    int pxl = w * 16 + (sB + s) * 2 + ph;                                      \
    float w00 = bf2f(ce[s].z & 0xffffu), w01 = bf2f(ce[s].z >> 16);            \
    float w10 = bf2f(ce[s].w & 0xffffu), w11 = bf2f(ce[s].w >> 16);            \
    float e0 = w00 * bf2f(g[s][0].x & 0xffffu) + w01 * bf2f(g[s][1].x & 0xffffu) \
             + w10 * bf2f(g[s][2].x & 0xffffu) + w11 * bf2f(g[s][3].x & 0xffffu); \
    float e1 = w00 * bf2f(g[s][0].x >> 16) + w01 * bf2f(g[s][1].x >> 16)       \
             + w10 * bf2f(g[s][2].x >> 16) + w11 * bf2f(g[s][3].x >> 16);      \
    float e2 = w00 * bf2f(g[s][0].y & 0xffffu) + w01 * bf2f(g[s][1].y & 0xffffu) \
             + w10 * bf2f(g[s][2].y & 0xffffu) + w11 * bf2f(g[s][3].y & 0xffffu); \
    float e3 = w00 * bf2f(g[s][0].y >> 16) + w01 * bf2f(g[s][1].y >> 16)       \
             + w10 * bf2f(g[s][2].y >> 16) + w11 * bf2f(g[s][3].y >> 16);      \
    unsigned r0 = (unsigned)f2bf(e0) | ((unsigned)f2bf(e1) << 16);             \
    unsigned r1 = (unsigned)f2bf(e2) | ((unsigned)f2bf(e3) << 16);             \
    *(uint2*)((char*)&s_smp[buf][0] +                                          \
              ((pxl * 256 + hl * 8) ^ ((pxl & 7) << 4))) = make_uint2(r0, r1); \
  }

#define DMFMA(ksB)                                                             \
  __builtin_amdgcn_s_setprio(1);                                               \
  _Pragma("unroll") for (int ks = ksB; ks < ksB + 2; ks++) {                   \
    bf16x8 bfr[4];                                                             \
    _Pragma("unroll") for (int n = 0; n < 4; n++) {                            \
      int pxr = n * 16 + row;                                                  \
      bfr[n] = *(const bf16x8*)((const char*)&s_smp[cur][0] +                  \
               ((pxr * 256 + ks * 64 + grp * 16) ^ ((pxr & 7) << 4)));         \
    }                                                                          \
    _Pragma("unroll") for (int m = 0; m < 2; m++)                              \
      _Pragma("unroll") for (int n = 0; n < 4; n++)                            \
        acc[m][n] = __builtin_amdgcn_mfma_f32_16x16x32_bf16(af[m][ks], bfr[n], acc[m][n], 0, 0, 0); \
  }                                                                            \
  __builtin_amdgcn_s_setprio(0);

  // prologue: gather k2=0 into buf0
  DISSUE(0, 0); DCOMMIT(0, 0);
  DISSUE(0, 4); DCOMMIT(4, 0);
  __syncthreads();
  int cur = 0;
  for (int k2 = 0; k2 < 9; k2++) {
    const unsigned short* wb = wpk + (size_t)(k2 * 8 + w * 2) * 2048;
#pragma unroll
    for (int m = 0; m < 2; m++)
#pragma unroll
      for (int ks = 0; ks < 4; ks++)
        af[m][ks] = *(const bf16x8*)&wb[(m * 4 + ks) * 512 + l * 8];
    if (k2 < 8) { DISSUE(k2 + 1, 0); }
    DMFMA(0);
    if (k2 < 8) { DCOMMIT(0, cur ^ 1); DISSUE(k2 + 1, 4); }
    DMFMA(2);
    if (k2 < 8) { DCOMMIT(4, cur ^ 1); }
    __syncthreads();
    cur ^= 1;
  }
#undef DISSUE
#undef DCOMMIT
#undef DMFMA

  // epilogue: write z NHWC fp32
#pragma unroll
  for (int m = 0; m < 2; m++)
#pragma unroll
    for (int n = 0; n < 4; n++) {
      int o = (w * 2 + m) * 16 + grp * 4;
      size_t px = (size_t)(b * HW) + p0 + n * 16 + row;
      float4 v = make_float4(acc[m][n][0], acc[m][n][1], acc[m][n][2], acc[m][n][3]);
      *(float4*)&z[px * CC + o] = v;
    }
}

// ---- BN stats stage 1 ----
__global__ __launch_bounds__(256) void bn_part(const float* __restrict__ z,
                                               float* __restrict__ part) {
  const int blk = blockIdx.x;   // 392
  const int tid = threadIdx.x;
  const int c4 = tid & 31, rg = tid >> 5;
  const float* base = z + (size_t)blk * 128 * CC;
  f32x4 s = (f32x4){0.f, 0.f, 0.f, 0.f};
  f32x4 q = (f32x4){0.f, 0.f, 0.f, 0.f};
#pragma unroll 4
  for (int i = 0; i < 16; i++) {
    f32x4 v = *(const f32x4*)&base[(size_t)(rg + i * 8) * CC + c4 * 4];
    s += v;
    q += v * v;
  }
  __shared__ float sm[8][128], sq[8][128];
  *(f32x4*)&sm[rg][c4 * 4] = s;
  *(f32x4*)&sq[rg][c4 * 4] = q;
  __syncthreads();
  if (tid < 128) {
    float a = 0.f, bsum = 0.f;
#pragma unroll
    for (int j = 0; j < 8; j++) { a += sm[j][tid]; bsum += sq[j][tid]; }
    part[blk * 256 + tid] = a;
    part[blk * 256 + 128 + tid] = bsum;
  }
}

// ---- BN stats stage 2 ----
__global__ void bn_fin(const float* __restrict__ part, const float* __restrict__ gamma,
                       const float* __restrict__ beta, float* __restrict__ stats) {
  int t = threadIdx.x;   // 128
  float s = 0.f, q = 0.f;
  for (int j = 0; j < 392; j++) { s += part[j * 256 + t]; q += part[j * 256 + 128 + t]; }
  float N = 50176.f;
  float m = s / N;
  float var = q / N - m * m;
  stats[t] = m;
  stats[128 + t] = rsqrtf(var + 1e-5f) * gamma[t];
  stats[256 + t] = beta[t];
}

// ---- BN+GELU, NHWC fp32 -> NHWC bf16 ----
__global__ __launch_bounds__(256) void bn_gelu_to_bf16(
    const float* __restrict__ z, const float* __restrict__ stats,
    unsigned short* __restrict__ yh) {
  int i4 = blockIdx.x * 256 + threadIdx.x;
  int c0 = (i4 & 31) * 4;
  f32x4 m = *(const f32x4*)&stats[c0];
  f32x4 rg = *(const f32x4*)&stats[128 + c0];
  f32x4 bt = *(const f32x4*)&stats[256 + c0];
  f32x4 v = ((const f32x4*)z)[i4];
  ushort4 o;
  o.x = f2bf(gelu((v[0] - m[0]) * rg[0] + bt[0]));
  o.y = f2bf(gelu((v[1] - m[1]) * rg[1] + bt[1]));
  o.z = f2bf(gelu((v[2] - m[2]) * rg[2] + bt[2]));
  o.w = f2bf(gelu((v[3] - m[3]) * rg[3] + bt[3]));
  *(ushort4*)&yh[(size_t)i4 * 4] = o;
}

// ---- final: BN+GELU on z2 NHWC, transpose to NCHW, +residual x ----
__global__ __launch_bounds__(256) void bn_gelu_final(
    const float* __restrict__ z, const float* __restrict__ stats,
    const float* __restrict__ x, float* __restrict__ out) {
  const int pt = blockIdx.x, b = blockIdx.y;
  const int p0 = pt * 16;
  const int tid = threadIdx.x;
  __shared__ float ls[16][129];
  {
    int cq = tid & 15, r = tid >> 4;
    const float* zr = z + ((size_t)(b * HW) + p0 + r) * CC + cq * 8;
    f32x4 v0 = *(const f32x4*)&zr[0];
    f32x4 v1 = *(const f32x4*)&zr[4];
    f32x4 m0 = *(const f32x4*)&stats[cq * 8];
    f32x4 m1 = *(const f32x4*)&stats[cq * 8 + 4];
    f32x4 r0 = *(const f32x4*)&stats[128 + cq * 8];
    f32x4 r1 = *(const f32x4*)&stats[128 + cq * 8 + 4];
    f32x4 b0 = *(const f32x4*)&stats[256 + cq * 8];
    f32x4 b1 = *(const f32x4*)&stats[256 + cq * 8 + 4];
#pragma unroll
    for (int j = 0; j < 4; j++) {
      ls[r][cq * 8 + j] = gelu((v0[j] - m0[j]) * r0[j] + b0[j]);
      ls[r][cq * 8 + 4 + j] = gelu((v1[j] - m1[j]) * r1[j] + b1[j]);
    }
  }
  __syncthreads();
  int c = tid & 127, half = tid >> 7;
  const float* xr = x + ((size_t)(b * CC) + c) * HW + p0 + half * 8;
  float* orow = out + ((size_t)(b * CC) + c) * HW + p0 + half * 8;
  float4 o1 = make_float4(ls[half * 8 + 0][c], ls[half * 8 + 1][c],
                          ls[half * 8 + 2][c], ls[half * 8 + 3][c]);
  float4 o2 = make_float4(ls[half * 8 + 4][c], ls[half * 8 + 5][c],
                          ls[half * 8 + 6][c], ls[half * 8 + 7][c]);
  float4 x1 = *(const float4*)&xr[0];
  float4 x2 = *(const float4*)&xr[4];
  o1.x += x1.x; o1.y += x1.y; o1.z += x1.z; o1.w += x1.w;
  o2.x += x2.x; o2.y += x2.y; o2.z += x2.z; o2.w += x2.w;
  *(float4*)&orow[0] = o1;
  *(float4*)&orow[4] = o2;
}

extern "C" void kernel_launch(void* const* d_in, const int* in_sizes, int n_in,
                              void* d_out, int out_size, void* d_ws, size_t ws_size,
                              hipStream_t stream) {
  const float* x = (const float*)d_in[0];
  const float* w_off1 = (const float*)d_in[1];
  const float* b_off1 = (const float*)d_in[2];
  const float* w_def1 = (const float*)d_in[3];
  const float* gamma1 = (const float*)d_in[4];
  const float* beta1 = (const float*)d_in[5];
  const float* w_off2 = (const float*)d_in[6];
  const float* b_off2 = (const float*)d_in[7];
  const float* w_def2 = (const float*)d_in[8];
  const float* gamma2 = (const float*)d_in[9];
  const float* beta2 = (const float*)d_in[10];
  float* out = (float*)d_out;

  char* ws = (char*)d_ws;
  unsigned short* xhb = (unsigned short*)ws;                 // 12,845,056 B (x NHWC bf16, later y1h)
  float* zb = (float*)(ws + 12845056);                       // 25,690,112 B
  float* offb = (float*)(ws + 38535168);                     //  3,612,672 B
  unsigned short* wpkb = (unsigned short*)(ws + 42147840);   //    294,912 B
  unsigned short* wopkb = (unsigned short*)(ws + 42442752);  //     73,728 B
  float* partb = (float*)(ws + 42516480);                    //    401,408 B
  float* statsb = (float*)(ws + 42917888);                   //      1,536 B

  to_nhwc<<<dim3(392, 4, 4), 256, 0, stream>>>(x, xhb);

  // ---- block 1 ----
  pack_woff<<<144, 256, 0, stream>>>(w_off1, wopkb);
  pack_wdef<<<576, 256, 0, stream>>>(w_def1, wpkb);
  offset_mfma<<<dim3(196, 4), 256, 0, stream>>>(xhb, wopkb, b_off1, offb);
  deform_mfma<<<dim3(196, 4), 256, 0, stream>>>(xhb, offb, wpkb, zb);
  bn_part<<<392, 256, 0, stream>>>(zb, partb);
  bn_fin<<<1, 128, 0, stream>>>(partb, gamma1, beta1, statsb);
  bn_gelu_to_bf16<<<6272, 256, 0, stream>>>(zb, statsb, xhb);

  // ---- block 2 ----
  pack_woff<<<144, 256, 0, stream>>>(w_off2, wopkb);
  pack_wdef<<<576, 256, 0, stream>>>(w_def2, wpkb);
  offset_mfma<<<dim3(196, 4), 256, 0, stream>>>(xhb, wopkb, b_off2, offb);
  deform_mfma<<<dim3(196, 4), 256, 0, stream>>>(xhb, offb, wpkb, zb);
  bn_part<<<392, 256, 0, stream>>>(zb, partb);
  bn_fin<<<1, 128, 0, stream>>>(partb, gamma2, beta2, statsb);
  bn_gelu_final<<<dim3(784, 4), 256, 0, stream>>>(zb, statsb, x, out);
}

// Round 4
// 205.756 us; speedup vs baseline: 5.9137x; 1.2157x over previous
//
#include <hip/hip_runtime.h>
#include <hip/hip_bf16.h>
#include <math.h>

#define HW 12544
#define CC 128
#define BB 4

typedef short bf16x8 __attribute__((ext_vector_type(8)));
typedef float f32x4 __attribute__((ext_vector_type(4)));

__device__ __forceinline__ float bf2f(unsigned int u) {
  union { unsigned int i; float f; } v; v.i = u << 16; return v.f;
}
__device__ __forceinline__ unsigned short f2bf(float f) {
  __hip_bfloat16 h = __float2bfloat16(f);
  return *reinterpret_cast<unsigned short*>(&h);
}
__device__ __forceinline__ float gelu(float v) {
  return 0.5f * v * (1.f + erff(v * 0.70710678118654752f));
}
__device__ __forceinline__ unsigned uc4(const uint4& v, int q) {
  return q == 0 ? v.x : q == 1 ? v.y : q == 2 ? v.z : v.w;
}

// ---- x NCHW fp32 -> xh NHWC bf16 ----
__global__ __launch_bounds__(256) void to_nhwc(const float* __restrict__ x,
                                               unsigned short* __restrict__ xh) {
  const int pt = blockIdx.x, ct = blockIdx.y, b = blockIdx.z;
  const int p0 = pt * 32, c0 = ct * 32;
  const int tid = threadIdx.x;
  __shared__ float ls[32][33];
  int col = tid & 31, r = tid >> 5;
#pragma unroll
  for (int i = 0; i < 4; i++) {
    int c = c0 + r + i * 8;
    ls[r + i * 8][col] = x[((size_t)(b * CC) + c) * HW + p0 + col];
  }
  __syncthreads();
  int px = tid >> 3, cq = (tid & 7) * 4;
  ushort4 v;
  v.x = f2bf(ls[cq + 0][px]);
  v.y = f2bf(ls[cq + 1][px]);
  v.z = f2bf(ls[cq + 2][px]);
  v.w = f2bf(ls[cq + 3][px]);
  *(ushort4*)&xh[((size_t)(b * HW) + p0 + px) * CC + c0 + cq] = v;
}

// ---- pack all 4 weight tensors -> fragment-line layouts ----
__global__ void pack_all(const float* __restrict__ wd1, const float* __restrict__ wo1,
                         const float* __restrict__ wd2, const float* __restrict__ wo2,
                         unsigned short* __restrict__ wpk1, unsigned short* __restrict__ wopk1,
                         unsigned short* __restrict__ wpk2, unsigned short* __restrict__ wopk2) {
  int i = blockIdx.x * 256 + threadIdx.x;   // 368640
  if (i < 294912) {
    int ii = (i < 147456) ? i : i - 147456;
    const float* src = (i < 147456) ? wd1 : wd2;
    unsigned short* dst = (i < 147456) ? wpk1 : wpk2;
    int j = ii & 7, lane = (ii >> 3) & 63, ks = (ii >> 9) & 3, mo = (ii >> 11) & 7, k2 = ii >> 14;
    int o = mo * 16 + (lane & 15), c = ks * 32 + ((lane >> 4) << 3) + j;
    dst[ii] = f2bf(src[(o * CC + c) * 9 + k2]);
  } else {
    int ii = i - 294912;   // 0..73727
    const float* src = (ii < 36864) ? wo1 : wo2;
    unsigned short* dst = (ii < 36864) ? wopk1 : wopk2;
    ii = (ii < 36864) ? ii : ii - 36864;
    int j = ii & 7, lane = (ii >> 3) & 63, ks = (ii >> 9) & 3, mo = (ii >> 11) & 1, k2 = ii >> 12;
    int o = mo * 16 + (lane & 15), c = ks * 32 + ((lane >> 4) << 3) + j;
    dst[ii] = (o < 18) ? f2bf(src[(o * CC + c) * 9 + k2]) : (unsigned short)0;
  }
}

// ---- offset conv via MFMA (barrier-free, dbuf, uint4 staging) ----
__global__ __launch_bounds__(256) void offset_mfma(
    const unsigned short* __restrict__ xh, const unsigned short* __restrict__ wopk,
    const float* __restrict__ boff, float* __restrict__ offs2) {
  const int bid0 = blockIdx.x;
  const int bid = (bid0 & 7) * 98 + (bid0 >> 3);   // XCD swizzle, 784%8==0
  const int b = bid / 196;
  const int p0 = (bid % 196) * 64;
  const int tid = threadIdx.x;
  const int l = tid & 63, w = tid >> 6;
  const int hl = l & 15, ph = l >> 4;
  const int row = l & 15, grp = l >> 4;
  __shared__ unsigned short s_smp[2][8192];
  const unsigned short* xb = xh + (size_t)b * HW * CC + hl * 8;
  f32x4 acc[2];
  acc[0] = (f32x4){0.f, 0.f, 0.f, 0.f};
  acc[1] = (f32x4){0.f, 0.f, 0.f, 0.f};
  uint4 g2[4];
  bf16x8 af[2][4];

#define OISSUE(K2T)                                                            \
  {                                                                            \
    int ky = (K2T) / 3, kx = (K2T) % 3;                                        \
    _Pragma("unroll") for (int s = 0; s < 4; s++) {                            \
      int pxl = w * 16 + s * 4 + ph;                                           \
      int p = p0 + pxl;                                                        \
      int ho = p / 112, wo = p - ho * 112;                                     \
      int y = ho + ky - 1, x = wo + kx - 1;                                    \
      uint4 t = make_uint4(0u, 0u, 0u, 0u);                                    \
      if (((unsigned)y < 112u) & ((unsigned)x < 112u))                         \
        t = *(const uint4*)&xb[(size_t)(y * 112 + x) * CC];                    \
      g2[s] = t;                                                               \
    }                                                                          \
  }

#define OCOMMIT(BNBUF)                                                         \
  _Pragma("unroll") for (int s = 0; s < 4; s++) {                              \
    int pxl = w * 16 + s * 4 + ph;                                             \
    *(uint4*)((char*)&s_smp[BNBUF][0] +                                        \
              ((pxl * 256 + hl * 16) ^ ((pxl & 7) << 4))) = g2[s];             \
  }

#define OMFMA(BCBUF, ksB)                                                      \
  __builtin_amdgcn_s_setprio(1);                                               \
  _Pragma("unroll") for (int ks = ksB; ks < ksB + 2; ks++) {                   \
    int pxr = w * 16 + row;                                                    \
    bf16x8 bfr = *(const bf16x8*)((const char*)&s_smp[BCBUF][0] +              \
                 ((pxr * 256 + ks * 64 + grp * 16) ^ ((pxr & 7) << 4)));       \
    _Pragma("unroll") for (int m = 0; m < 2; m++)                              \
      acc[m] = __builtin_amdgcn_mfma_f32_16x16x32_bf16(af[m][ks], bfr, acc[m], 0, 0, 0); \
  }                                                                            \
  __builtin_amdgcn_s_setprio(0);

#define OLOADW(K2T)                                                            \
  {                                                                            \
    const unsigned short* wb = wopk + (size_t)(K2T) * 4096;                    \
    _Pragma("unroll") for (int m = 0; m < 2; m++)                              \
      _Pragma("unroll") for (int ks = 0; ks < 4; ks++)                         \
        af[m][ks] = *(const bf16x8*)&wb[(m * 4 + ks) * 512 + l * 8];           \
  }

#define OITER(K2T, BC, BN)                                                     \
  {                                                                            \
    if ((K2T) < 8) { OISSUE((K2T) + 1); }                                      \
    OMFMA(BC, 0);                                                              \
    if ((K2T) < 8) { OCOMMIT(BN); }                                            \
    OMFMA(BC, 2);                                                              \
    if ((K2T) < 8) { OLOADW((K2T) + 1); }                                      \
  }

  OISSUE(0); OCOMMIT(0); OLOADW(0);
  OITER(0, 0, 1) OITER(1, 1, 0) OITER(2, 0, 1) OITER(3, 1, 0) OITER(4, 0, 1)
  OITER(5, 1, 0) OITER(6, 0, 1) OITER(7, 1, 0) OITER(8, 0, 1)
#undef OISSUE
#undef OCOMMIT
#undef OMFMA
#undef OLOADW
#undef OITER

  int p = p0 + w * 16 + row;
  {
    float2 w0 = make_float2(acc[0][0] + boff[grp * 4 + 0], acc[0][1] + boff[grp * 4 + 1]);
    float2 w1 = make_float2(acc[0][2] + boff[grp * 4 + 2], acc[0][3] + boff[grp * 4 + 3]);
    *(float2*)&offs2[((size_t)(b * 9 + grp * 2) * HW + p) * 2] = w0;
    *(float2*)&offs2[((size_t)(b * 9 + grp * 2 + 1) * HW + p) * 2] = w1;
    if (grp == 0) {
      float2 w2 = make_float2(acc[1][0] + boff[16], acc[1][1] + boff[17]);
      *(float2*)&offs2[((size_t)(b * 9 + 8) * HW + p) * 2] = w2;
    }
  }
}

// ---- deformable conv via MFMA: uint4 gathers, fused BN partials, bf16 z ----
__global__ __launch_bounds__(256, 3) void deform_mfma(
    const unsigned short* __restrict__ xh, const float* __restrict__ offs2,
    const unsigned short* __restrict__ wpk, unsigned short* __restrict__ zh,
    float* __restrict__ part) {
  const int bid0 = blockIdx.x;
  const int bid = (bid0 & 7) * 98 + (bid0 >> 3);   // XCD swizzle
  const int b = bid / 196;
  const int p0 = (bid % 196) * 64;
  const int tid = threadIdx.x;
  const int l = tid & 63, w = tid >> 6;
  const int hl = l & 15, ph = l >> 4;
  const int row = l & 15, grp = l >> 4;
  __shared__ unsigned short s_smp[2][8192];
  __shared__ uint4 s_coord[9][64];

  // coord precompute: clamped u16 corner indices + bf16 corner weights
  for (int e = tid; e < 576; e += 256) {
    int k2 = e >> 6, px = e & 63;
    int p = p0 + px;
    int ho = p / 112, wo = p - ho * 112;
    int ky = k2 / 3, kx = k2 - 3 * ky;
    float2 dv = *(const float2*)&offs2[((size_t)(b * 9 + k2) * HW + p) * 2];
    float py = (float)(ho + ky - 1) + dv.x;
    float pxf = (float)(wo + kx - 1) + dv.y;
    float y0f = floorf(py), x0f = floorf(pxf);
    float wy = py - y0f, wx = pxf - x0f;
    int y0 = (int)y0f, x0 = (int)x0f;
    int y1 = y0 + 1, x1 = x0 + 1;
    bool iy0 = ((unsigned)y0 < 112u), iy1 = ((unsigned)y1 < 112u);
    bool ix0 = ((unsigned)x0 < 112u), ix1 = ((unsigned)x1 < 112u);
    float v00 = (iy0 & ix0) ? (1.f - wy) * (1.f - wx) : 0.f;
    float v01 = (iy0 & ix1) ? (1.f - wy) * wx : 0.f;
    float v10 = (iy1 & ix0) ? wy * (1.f - wx) : 0.f;
    float v11 = (iy1 & ix1) ? wy * wx : 0.f;
    int y0c = min(max(y0, 0), 111), y1c = min(max(y1, 0), 111);
    int x0c = min(max(x0, 0), 111), x1c = min(max(x1, 0), 111);
    uint4 ce;
    ce.x = (unsigned)(y0c * 112 + x0c) | ((unsigned)(y0c * 112 + x1c) << 16);
    ce.y = (unsigned)(y1c * 112 + x0c) | ((unsigned)(y1c * 112 + x1c) << 16);
    ce.z = (unsigned)f2bf(v00) | ((unsigned)f2bf(v01) << 16);
    ce.w = (unsigned)f2bf(v10) | ((unsigned)f2bf(v11) << 16);
    s_coord[k2][px] = ce;
  }

  const unsigned short* xb = xh + (size_t)b * HW * CC + hl * 8;
  f32x4 acc[2][4];
#pragma unroll
  for (int m = 0; m < 2; m++)
#pragma unroll
    for (int n = 0; n < 4; n++) acc[m][n] = (f32x4){0.f, 0.f, 0.f, 0.f};
  uint4 g[4][4];
  uint2 wts[4];
  bf16x8 af[2][4];
  __syncthreads();

#define DISSUE(K2T)                                                            \
  _Pragma("unroll") for (int s = 0; s < 4; s++) {                              \
    int pxl = w * 16 + s * 4 + ph;                                             \
    uint4 cc = s_coord[K2T][pxl];                                              \
    wts[s] = make_uint2(cc.z, cc.w);                                           \
    g[s][0] = *(const uint4*)&xb[(size_t)(cc.x & 0xffffu) * CC];               \
    g[s][1] = *(const uint4*)&xb[(size_t)(cc.x >> 16) * CC];                   \
    g[s][2] = *(const uint4*)&xb[(size_t)(cc.y & 0xffffu) * CC];               \
    g[s][3] = *(const uint4*)&xb[(size_t)(cc.y >> 16) * CC];                   \
  }

#define DCOMMIT(BNBUF)                                                         \
  _Pragma("unroll") for (int s = 0; s < 4; s++) {                              \
    int pxl = w * 16 + s * 4 + ph;                                             \
    float w00 = bf2f(wts[s].x & 0xffffu), w01 = bf2f(wts[s].x >> 16);          \
    float w10 = bf2f(wts[s].y & 0xffffu), w11 = bf2f(wts[s].y >> 16);          \
    unsigned rr[4];                                                            \
    _Pragma("unroll") for (int q = 0; q < 4; q++) {                            \
      unsigned a0 = uc4(g[s][0], q), a1 = uc4(g[s][1], q);                     \
      unsigned a2 = uc4(g[s][2], q), a3 = uc4(g[s][3], q);                     \
      float elo = w00 * bf2f(a0 & 0xffffu) + w01 * bf2f(a1 & 0xffffu)          \
                + w10 * bf2f(a2 & 0xffffu) + w11 * bf2f(a3 & 0xffffu);         \
      float ehi = w00 * bf2f(a0 >> 16) + w01 * bf2f(a1 >> 16)                  \
                + w10 * bf2f(a2 >> 16) + w11 * bf2f(a3 >> 16);                 \
      rr[q] = (unsigned)f2bf(elo) | ((unsigned)f2bf(ehi) << 16);               \
    }                                                                          \
    *(uint4*)((char*)&s_smp[BNBUF][0] +                                        \
              ((pxl * 256 + hl * 16) ^ ((pxl & 7) << 4))) =                    \
        make_uint4(rr[0], rr[1], rr[2], rr[3]);                                \
  }

#define DMFMA(BCBUF, ksB)                                                      \
  __builtin_amdgcn_s_setprio(1);                                               \
  _Pragma("unroll") for (int ks = ksB; ks < ksB + 2; ks++) {                   \
    bf16x8 bfr[4];                                                             \
    _Pragma("unroll") for (int n = 0; n < 4; n++) {                            \
      int pxr = n * 16 + row;                                                  \
      bfr[n] = *(const bf16x8*)((const char*)&s_smp[BCBUF][0] +                \
               ((pxr * 256 + ks * 64 + grp * 16) ^ ((pxr & 7) << 4)));         \
    }                                                                          \
    _Pragma("unroll") for (int m = 0; m < 2; m++)                              \
      _Pragma("unroll") for (int n = 0; n < 4; n++)                            \
        acc[m][n] = __builtin_amdgcn_mfma_f32_16x16x32_bf16(af[m][ks], bfr[n], acc[m][n], 0, 0, 0); \
  }                                                                            \
  __builtin_amdgcn_s_setprio(0);

#define DLOADW(K2T)                                                            \
  {                                                                            \
    const unsigned short* wb = wpk + (size_t)((K2T) * 8 + w * 2) * 2048;       \
    _Pragma("unroll") for (int m = 0; m < 2; m++)                              \
      _Pragma("unroll") for (int ks = 0; ks < 4; ks++)                         \
        af[m][ks] = *(const bf16x8*)&wb[(m * 4 + ks) * 512 + l * 8];           \
  }

#define DITER(K2T, BC, BN)                                                     \
  {                                                                            \
    if ((K2T) < 8) { DISSUE((K2T) + 1); }                                      \
    DMFMA(BC, 0);                                                              \
    if ((K2T) < 8) { DCOMMIT(BN); }                                            \
    DMFMA(BC, 2);                                                              \
    if ((K2T) < 8) { DLOADW((K2T) + 1); __syncthreads(); }                     \
  }

  DISSUE(0); DCOMMIT(0); DLOADW(0);
  __syncthreads();
  DITER(0, 0, 1) DITER(1, 1, 0) DITER(2, 0, 1) DITER(3, 1, 0) DITER(4, 0, 1)
  DITER(5, 1, 0) DITER(6, 0, 1) DITER(7, 1, 0) DITER(8, 0, 1)
#undef DISSUE
#undef DCOMMIT
#undef DMFMA
#undef DLOADW
#undef DITER

  // z write (bf16 NHWC)
#pragma unroll
  for (int m = 0; m < 2; m++)
#pragma unroll
    for (int n = 0; n < 4; n++) {
      int o = (w * 2 + m) * 16 + grp * 4;
      size_t px = (size_t)(b * HW) + p0 + n * 16 + row;
      unsigned lo = (unsigned)f2bf(acc[m][n][0]) | ((unsigned)f2bf(acc[m][n][1]) << 16);
      unsigned hi = (unsigned)f2bf(acc[m][n][2]) | ((unsigned)f2bf(acc[m][n][3]) << 16);
      *(uint2*)&zh[px * CC + o] = make_uint2(lo, hi);
    }

  // fused BN partials: per-channel sum/sumsq over this block's 64 px
  float sv[8], qv[8];
#pragma unroll
  for (int m = 0; m < 2; m++)
#pragma unroll
    for (int r = 0; r < 4; r++) {
      float s = 0.f, q = 0.f;
#pragma unroll
      for (int n = 0; n < 4; n++) { float v = acc[m][n][r]; s += v; q += v * v; }
      sv[m * 4 + r] = s; qv[m * 4 + r] = q;
    }
#pragma unroll
  for (int d = 1; d < 16; d <<= 1)
#pragma unroll
    for (int i = 0; i < 8; i++) {
      sv[i] += __shfl_xor(sv[i], d);
      qv[i] += __shfl_xor(qv[i], d);
    }
  if (row == 0) {
#pragma unroll
    for (int m = 0; m < 2; m++)
#pragma unroll
      for (int r = 0; r < 4; r++) {
        int ch = (w * 2 + m) * 16 + grp * 4 + r;
        part[(size_t)ch * 784 + bid] = sv[m * 4 + r];
        part[(size_t)(128 + ch) * 784 + bid] = qv[m * 4 + r];
      }
  }
}

// ---- BN stats: reduce 784 block partials per channel ----
__global__ __launch_bounds__(256) void bn_fin(const float* __restrict__ part,
                                              const float* __restrict__ gamma,
                                              const float* __restrict__ beta,
                                              float* __restrict__ stats) {
  const int c = blockIdx.x, t = threadIdx.x;
  float s = 0.f, q = 0.f;
  for (int j = t; j < 784; j += 256) {
    s += part[(size_t)c * 784 + j];
    q += part[(size_t)(128 + c) * 784 + j];
  }
  __shared__ float ss[256], sq2[256];
  ss[t] = s; sq2[t] = q;
  __syncthreads();
  for (int d = 128; d > 0; d >>= 1) {
    if (t < d) { ss[t] += ss[t + d]; sq2[t] += sq2[t + d]; }
    __syncthreads();
  }
  if (t == 0) {
    float N = 50176.f;
    float m = ss[0] / N;
    float var = sq2[0] / N - m * m;
    stats[c] = m;
    stats[128 + c] = rsqrtf(var + 1e-5f) * gamma[c];
    stats[256 + c] = beta[c];
  }
}

// ---- BN+GELU, z bf16 NHWC -> y bf16 NHWC (feeds block 2) ----
__global__ __launch_bounds__(256) void bn_gelu_to_bf16(
    const unsigned short* __restrict__ zh, const float* __restrict__ stats,
    unsigned short* __restrict__ yh) {
  int i = blockIdx.x * 256 + threadIdx.x;   // 802816 exact
  int c0 = (i & 15) * 8;
  uint4 zv = ((const uint4*)zh)[i];
  f32x4 m0 = *(const f32x4*)&stats[c0], m1 = *(const f32x4*)&stats[c0 + 4];
  f32x4 r0 = *(const f32x4*)&stats[128 + c0], r1 = *(const f32x4*)&stats[128 + c0 + 4];
  f32x4 b0 = *(const f32x4*)&stats[256 + c0], b1 = *(const f32x4*)&stats[256 + c0 + 4];
  float v[8] = {bf2f(zv.x & 0xffffu), bf2f(zv.x >> 16), bf2f(zv.y & 0xffffu), bf2f(zv.y >> 16),
                bf2f(zv.z & 0xffffu), bf2f(zv.z >> 16), bf2f(zv.w & 0xffffu), bf2f(zv.w >> 16)};
  unsigned o[4];
#pragma unroll
  for (int j = 0; j < 4; j++) {
    float mj0 = (j < 2) ? m0[j * 2] : m1[j * 2 - 4], mj1 = (j < 2) ? m0[j * 2 + 1] : m1[j * 2 - 3];
    float rj0 = (j < 2) ? r0[j * 2] : r1[j * 2 - 4], rj1 = (j < 2) ? r0[j * 2 + 1] : r1[j * 2 - 3];
    float bj0 = (j < 2) ? b0[j * 2] : b1[j * 2 - 4], bj1 = (j < 2) ? b0[j * 2 + 1] : b1[j * 2 - 3];
    float e0 = gelu((v[j * 2] - mj0) * rj0 + bj0);
    float e1 = gelu((v[j * 2 + 1] - mj1) * rj1 + bj1);
    o[j] = (unsigned)f2bf(e0) | ((unsigned)f2bf(e1) << 16);
  }
  ((uint4*)yh)[i] = make_uint4(o[0], o[1], o[2], o[3]);
}

// ---- final: BN+GELU on z2 bf16 NHWC, transpose to NCHW, +residual x ----
__global__ __launch_bounds__(256) void bn_gelu_final(
    const unsigned short* __restrict__ zh, const float* __restrict__ stats,
    const float* __restrict__ x, float* __restrict__ out) {
  const int pt = blockIdx.x, b = blockIdx.y;
  const int p0 = pt * 16;
  const int tid = threadIdx.x;
  __shared__ float ls[16][129];
  {
    int cq = tid & 15, r = tid >> 4;
    uint4 zv = *(const uint4*)&zh[((size_t)(b * HW) + p0 + r) * CC + cq * 8];
    float v[8] = {bf2f(zv.x & 0xffffu), bf2f(zv.x >> 16), bf2f(zv.y & 0xffffu), bf2f(zv.y >> 16),
                  bf2f(zv.z & 0xffffu), bf2f(zv.z >> 16), bf2f(zv.w & 0xffffu), bf2f(zv.w >> 16)};
    f32x4 m0 = *(const f32x4*)&stats[cq * 8], m1 = *(const f32x4*)&stats[cq * 8 + 4];
    f32x4 r0 = *(const f32x4*)&stats[128 + cq * 8], r1 = *(const f32x4*)&stats[128 + cq * 8 + 4];
    f32x4 b0 = *(const f32x4*)&stats[256 + cq * 8], b1 = *(const f32x4*)&stats[256 + cq * 8 + 4];
#pragma unroll
    for (int j = 0; j < 4; j++) {
      ls[r][cq * 8 + j] = gelu((v[j] - m0[j]) * r0[j] + b0[j]);
      ls[r][cq * 8 + 4 + j] = gelu((v[4 + j] - m1[j]) * r1[j] + b1[j]);
    }
  }
  __syncthreads();
  int c = tid & 127, half = tid >> 7;
  const float* xr = x + ((size_t)(b * CC) + c) * HW + p0 + half * 8;
  float* orow = out + ((size_t)(b * CC) + c) * HW + p0 + half * 8;
  float4 o1 = make_float4(ls[half * 8 + 0][c], ls[half * 8 + 1][c],
                          ls[half * 8 + 2][c], ls[half * 8 + 3][c]);
  float4 o2 = make_float4(ls[half * 8 + 4][c], ls[half * 8 + 5][c],
                          ls[half * 8 + 6][c], ls[half * 8 + 7][c]);
  float4 x1 = *(const float4*)&xr[0];
  float4 x2 = *(const float4*)&xr[4];
  o1.x += x1.x; o1.y += x1.y; o1.z += x1.z; o1.w += x1.w;
  o2.x += x2.x; o2.y += x2.y; o2.z += x2.z; o2.w += x2.w;
  *(float4*)&orow[0] = o1;
  *(float4*)&orow[4] = o2;
}

extern "C" void kernel_launch(void* const* d_in, const int* in_sizes, int n_in,
                              void* d_out, int out_size, void* d_ws, size_t ws_size,
                              hipStream_t stream) {
  const float* x = (const float*)d_in[0];
  const float* w_off1 = (const float*)d_in[1];
  const float* b_off1 = (const float*)d_in[2];
  const float* w_def1 = (const float*)d_in[3];
  const float* gamma1 = (const float*)d_in[4];
  const float* beta1 = (const float*)d_in[5];
  const float* w_off2 = (const float*)d_in[6];
  const float* b_off2 = (const float*)d_in[7];
  const float* w_def2 = (const float*)d_in[8];
  const float* gamma2 = (const float*)d_in[9];
  const float* beta2 = (const float*)d_in[10];
  float* out = (float*)d_out;

  char* ws = (char*)d_ws;
  unsigned short* xhb = (unsigned short*)ws;                  // 12,845,056 B (x NHWC bf16, later y1h)
  unsigned short* zhb = (unsigned short*)(ws + 12845056);     // 12,845,056 B (z bf16 NHWC)
  float* offb = (float*)(ws + 25690112);                      //  3,612,672 B
  unsigned short* wpk1 = (unsigned short*)(ws + 29302784);    //    294,912 B
  unsigned short* wpk2 = (unsigned short*)(ws + 29597696);    //    294,912 B
  unsigned short* wopk1 = (unsigned short*)(ws + 29892608);   //     73,728 B
  unsigned short* wopk2 = (unsigned short*)(ws + 29966336);   //     73,728 B
  float* partb = (float*)(ws + 30040064);                     //    802,816 B
  float* statsb = (float*)(ws + 30842880);                    //      1,536 B

  to_nhwc<<<dim3(392, 4, 4), 256, 0, stream>>>(x, xhb);
  pack_all<<<1440, 256, 0, stream>>>(w_def1, w_off1, w_def2, w_off2,
                                     wpk1, wopk1, wpk2, wopk2);

  // ---- block 1 ----
  offset_mfma<<<784, 256, 0, stream>>>(xhb, wopk1, b_off1, offb);
  deform_mfma<<<784, 256, 0, stream>>>(xhb, offb, wpk1, zhb, partb);
  bn_fin<<<128, 256, 0, stream>>>(partb, gamma1, beta1, statsb);
  bn_gelu_to_bf16<<<3136, 256, 0, stream>>>(zhb, statsb, xhb);

  // ---- block 2 ----
  offset_mfma<<<784, 256, 0, stream>>>(xhb, wopk2, b_off2, offb);
  deform_mfma<<<784, 256, 0, stream>>>(xhb, offb, wpk2, zhb, partb);
  bn_fin<<<128, 256, 0, stream>>>(partb, gamma2, beta2, statsb);
  bn_gelu_final<<<dim3(784, 4), 256, 0, stream>>>(zhb, statsb, x, out);
}